// Round 3
// baseline (471.913 us; speedup 1.0000x reference)
//
#include <hip/hip_runtime.h>
#include <math.h>

// Problem constants
#define BATCH 128
#define NPER 400
#define EPG 6400
#define NEDGE 819200
#define F_IN 400
#define HD 128
#define K1 320
#define K2 256
#define K3 205

typedef __bf16 bf16x8 __attribute__((ext_vector_type(8)));
typedef float f32x4 __attribute__((ext_vector_type(4)));

__device__ __forceinline__ unsigned short f2bf(float f) {
    unsigned u = __builtin_bit_cast(unsigned, f);
    unsigned r = u + 0x7fffu + ((u >> 16) & 1u);
    return (unsigned short)(r >> 16);
}
__device__ __forceinline__ float bf2f(unsigned short s) {
    unsigned u = ((unsigned)s) << 16;
    return __builtin_bit_cast(float, u);
}

// async global -> LDS copy, 16 bytes per lane (global_load_lds_dwordx4).
// LDS dest is wave-uniform base + lane*16 (HW behavior); global src is per-lane.
__device__ __forceinline__ void async_ld16(const void* g, void* lds) {
    __builtin_amdgcn_global_load_lds(
        (const __attribute__((address_space(1))) unsigned int*)g,
        (__attribute__((address_space(3))) unsigned int*)lds, 16, 0, 0);
}

// ---------------- workspace layout ----------------
static constexpr size_t SZ_TREL = 51200ull * 128 * 4;
static constexpr size_t OFF_TREL = 0;
static constexpr size_t OFF_H    = OFF_TREL + SZ_TREL;
static constexpr size_t OFF_HP   = OFF_H + SZ_TREL;
static constexpr size_t OFF_SC   = OFF_HP + 40960ull * 128 * 4;
static constexpr size_t OFF_ES   = OFF_SC + 51200ull * 4;
static constexpr size_t OFF_ED   = OFF_ES + (size_t)NEDGE * 4;
static constexpr size_t OFF_EM   = OFF_ED + (size_t)NEDGE * 4;
static constexpr size_t OFF_Z    = OFF_EM + (size_t)NEDGE * 4;
static constexpr size_t OFF_COFF = OFF_Z + 128ull * 256 * 4;
static constexpr size_t OFF_CDEG = OFF_COFF + 51200ull * 4;
static constexpr size_t OFF_CSRC = OFF_CDEG + 51200ull * 4;
static constexpr size_t OFF_W1H  = OFF_CSRC + (size_t)NEDGE * 4;   // 16*13*512 shorts
static constexpr size_t OFF_W1L  = OFF_W1H + 16ull * 13 * 512 * 2;
static constexpr size_t OFF_W2H  = OFF_W1L + 16ull * 13 * 512 * 2;
static constexpr size_t OFF_W2L  = OFF_W2H + 16ull * 4 * 512 * 2;
static constexpr size_t OFF_W3H  = OFF_W2L + 16ull * 4 * 512 * 2;
static constexpr size_t OFF_W3L  = OFF_W3H + 16ull * 4 * 512 * 2;

// ---------------- weight split + fragment-tile prep (all 3 layers) ---------
// chunk[(n_tile*Ks + s)*512 + lane*8 + e] = B[n_tile*16 + (lane&15)][s*32 + (lane>>4)*8 + e]
__global__ __launch_bounds__(64) void prep_w_all(
    const float* __restrict__ Wrel1, const float* __restrict__ Wroot1,
    const float* __restrict__ Wrel2, const float* __restrict__ Wroot2,
    const float* __restrict__ Wrel3, const float* __restrict__ Wroot3,
    unsigned short* __restrict__ b1h, unsigned short* __restrict__ b1l,
    unsigned short* __restrict__ b2h, unsigned short* __restrict__ b2l,
    unsigned short* __restrict__ b3h, unsigned short* __restrict__ b3l) {
    const int layer = blockIdx.z;
    const int s = blockIdx.x;
    const int ntile = blockIdx.y;
    const int Ks = (layer == 0) ? 13 : 4;
    const int Kd = (layer == 0) ? F_IN : HD;
    if (s >= Ks) return;
    const float* Wrel  = (layer == 0) ? Wrel1  : (layer == 1) ? Wrel2  : Wrel3;
    const float* Wroot = (layer == 0) ? Wroot1 : (layer == 1) ? Wroot2 : Wroot3;
    unsigned short* bh = (layer == 0) ? b1h : (layer == 1) ? b2h : b3h;
    unsigned short* bl = (layer == 0) ? b1l : (layer == 1) ? b2l : b3l;
    const int t = threadIdx.x;
    const int rowin = t & 15, qd = t >> 4;
    const int n = ntile * 16 + rowin;
    const int k = s * 32 + qd * 8;
    const float* src = (n < 128) ? &Wrel[(n & 127) * Kd] : &Wroot[(n & 127) * Kd];
    unsigned short hv[8], lv[8];
#pragma unroll
    for (int e = 0; e < 8; e++) {
        float f = (k + e < Kd) ? src[k + e] : 0.f;
        unsigned short hi = f2bf(f);
        hv[e] = hi;
        lv[e] = f2bf(f - bf2f(hi));
    }
    size_t o = ((size_t)ntile * Ks + s) * 512 + (size_t)t * 8;
#pragma unroll
    for (int e = 0; e < 8; e++) { bh[o + e] = hv[e]; bl[o + e] = lv[e]; }
}

// ---------------- MFMA GEMM (bf16x3 split, LDS triple-buffer, counted vmcnt)
// 1-D grid M/64. Block 256 thr = 4 waves; all waves share the SAME 64 A-rows,
// staged via global_load_lds into a 3-deep LDS pipeline.
// Occupancy-first design: no B register double-buffer (saves 32 VGPRs) and
// __launch_bounds__(256,3) => <=170 regs/wave incl. 64 acc-AGPRs => 3 blocks/CU.
// TLP (3 waves/SIMD) hides ds_read + B-load latency; counted vmcnt keeps the
// A-DMA pipeline (issued 2 steps ahead) in flight across barriers.
// Load-issue order per step: B(s) FIRST, then DMA(s+2) -- in-order retirement
// means the compiler's pre-MFMA wait is vmcnt(2), never draining DMA(s+2).
template <int Ks, int Kd>
__global__ __launch_bounds__(256, 3) void gemm_mfma(
    const float* __restrict__ A,
    const unsigned short* __restrict__ bh_p, const unsigned short* __restrict__ bl_p,
    float* __restrict__ t_rel, float* __restrict__ h) {
    __shared__ float Alds[3][2048];   // 3 x 8KB
    const int tid = threadIdx.x;
    const int lane = tid & 63;
    const int wv = tid >> 6;
    const int lm = lane & 15;
    const int qd = (lane >> 4) & 3;
    const int m0 = blockIdx.x * 64;
    const int nt0 = wv * 4;

    // ---- staging geometry (constant per lane) ----
    const int srow = wv * 8 + (lane >> 3);            // + p*32
    const int sgr  = (lane & 7) ^ ((lane >> 3) & 7);  // granule to FETCH (pre-swizzle)
    const size_t amax = (size_t)gridDim.x * 64 * Kd * 4 - 16;  // clamp for K tail
    const char* Abyte = (const char*)A;

    // ---- compute-side LDS byte offsets (constant per lane) ----
    const int ga = (((2 * qd)     ^ (lm & 7)) << 4);
    const int gb = (((2 * qd + 1) ^ (lm & 7)) << 4);

    f32x4 acc[4][4];
#pragma unroll
    for (int i = 0; i < 4; i++)
#pragma unroll
        for (int j = 0; j < 4; j++) acc[i][j] = (f32x4){0.f, 0.f, 0.f, 0.f};

    auto stage = [&](int buf, int s) {
#pragma unroll
        for (int p = 0; p < 2; ++p) {
            const int row = srow + p * 32;
            size_t go = (size_t)(m0 + row) * Kd * 4 + (size_t)s * 128
                        + ((size_t)sgr << 4);
            if (go > amax) go = amax;   // K-tail: harmless duplicate fetch
            async_ld16(Abyte + go, &Alds[buf][p * 1024 + wv * 256]);
        }
    };

    // ---- prologue: DMA(0), DMA(1) ----
    stage(0, 0);
    if (Ks > 1) stage(1, 1);

#pragma unroll
    for (int s = 0; s < Ks; ++s) {
        // ---- counted wait + barrier: buf[s] ready; DMA(s+1) stays in flight
        if (s + 1 < Ks) asm volatile("s_waitcnt vmcnt(2)" ::: "memory");
        else            asm volatile("s_waitcnt vmcnt(0)" ::: "memory");
        __builtin_amdgcn_s_barrier();

        // ---- B fragment loads for THIS step (L2/L3-hot; latency hidden by
        //      the ds_read+split chain below plus cross-wave TLP) ----
        bf16x8 bh_c[4], bl_c[4];
#pragma unroll
        for (int j = 0; j < 4; j++)
            bh_c[j] = *(const bf16x8*)&bh_p[((size_t)(nt0 + j) * Ks + s) * 512 + lane * 8];
#pragma unroll
        for (int j = 0; j < 4; j++)
            bl_c[j] = *(const bf16x8*)&bl_p[((size_t)(nt0 + j) * Ks + s) * 512 + lane * 8];
        // ---- then the 2-ahead DMA (must be issued AFTER the B loads) ----
        if (s + 2 < Ks) stage((s + 2) % 3, s + 2);

        // ---- A: LDS fragment reads + in-register split ----
        const char* Ab = (const char*)&Alds[s % 3][0];
        bf16x8 ah[4], al[4];
#pragma unroll
        for (int i = 0; i < 4; i++) {
            float4 f0, f1;
            if (s * 32 + qd * 8 < Kd) {
                const char* base = Ab + (lm + i * 16) * 128;
                f0 = *(const float4*)(base + ga);
                f1 = *(const float4*)(base + gb);
            } else {
                f0 = make_float4(0.f, 0.f, 0.f, 0.f);
                f1 = f0;
            }
            float fe[8] = {f0.x, f0.y, f0.z, f0.w, f1.x, f1.y, f1.z, f1.w};
#pragma unroll
            for (int e = 0; e < 8; e++) {
                __bf16 hb = (__bf16)fe[e];
                ah[i][e] = hb;
                al[i][e] = (__bf16)(fe[e] - (float)hb);
            }
        }
        // ---- MFMA: hi*hi + lo*hi + hi*lo (order preserved for numerics) ----
        __builtin_amdgcn_s_setprio(1);
#pragma unroll
        for (int j = 0; j < 4; j++)
#pragma unroll
            for (int i = 0; i < 4; i++)
                acc[i][j] = __builtin_amdgcn_mfma_f32_16x16x32_bf16(
                    ah[i], bh_c[j], acc[i][j], 0, 0, 0);
#pragma unroll
        for (int j = 0; j < 4; j++)
#pragma unroll
            for (int i = 0; i < 4; i++)
                acc[i][j] = __builtin_amdgcn_mfma_f32_16x16x32_bf16(
                    al[i], bh_c[j], acc[i][j], 0, 0, 0);
#pragma unroll
        for (int j = 0; j < 4; j++)
#pragma unroll
            for (int i = 0; i < 4; i++)
                acc[i][j] = __builtin_amdgcn_mfma_f32_16x16x32_bf16(
                    ah[i], bl_c[j], acc[i][j], 0, 0, 0);
        __builtin_amdgcn_s_setprio(0);
    }
    // ---- epilogue: C/D layout col=lane&15, row=qd*4+reg ----
    float* out = (wv < 2) ? t_rel : h;
    const int colbase = (wv & 1) * 64;
#pragma unroll
    for (int i = 0; i < 4; i++)
#pragma unroll
        for (int j = 0; j < 4; j++) {
            int row = m0 + i * 16 + qd * 4;
            int col = colbase + j * 16 + lm;
#pragma unroll
            for (int r = 0; r < 4; r++)
                out[(size_t)(row + r) * 128 + col] = acc[i][j][r];
        }
}

// ---------------- CSR build for layer 1 (original edges, no mask) ----------
__global__ __launch_bounds__(1024) void csr_build0(
    const int* __restrict__ gsrc, const int* __restrict__ gdst,
    int* __restrict__ csr_off, int* __restrict__ csr_deg, int* __restrict__ csr_src) {
    __shared__ int cnt[NPER];
    __shared__ int cur[NPER];
    __shared__ int sscan[512];
    const int g = blockIdx.x;
    const int t = threadIdx.x;
    for (int i = t; i < NPER; i += 1024) cnt[i] = 0;
    __syncthreads();
    for (int e = t; e < EPG; e += 1024) {
        int dl = gdst[g * EPG + e] - g * NPER;
        atomicAdd(&cnt[dl], 1);
    }
    __syncthreads();
    if (t < 512) sscan[t] = (t < NPER) ? cnt[t] : 0;
    __syncthreads();
    for (int d = 1; d < 512; d <<= 1) {
        int v = 0;
        if (t < 512 && t >= d) v = sscan[t - d];
        __syncthreads();
        if (t < 512 && t >= d) sscan[t] += v;
        __syncthreads();
    }
    if (t < NPER) {
        int excl = (t == 0) ? 0 : sscan[t - 1];
        int st = g * EPG + excl;
        csr_off[g * NPER + t] = st;
        csr_deg[g * NPER + t] = cnt[t];
        cur[t] = st;
    }
    __syncthreads();
    for (int e = t; e < EPG; e += 1024) {
        int eg = g * EPG + e;
        int dl = gdst[eg] - g * NPER;
        int slot = atomicAdd(&cur[dl], 1);
        csr_src[slot] = gsrc[eg];
    }
}

// ---------------- Aggregation (gather) + combine + relu + score ------------
__global__ __launch_bounds__(256) void agg_score(
    const float* __restrict__ t_rel,
    const int* __restrict__ csr_off, const int* __restrict__ csr_deg,
    const int* __restrict__ csr_src,
    const float* __restrict__ bias, const float* __restrict__ pw,
    float* __restrict__ h, float* __restrict__ sc, int npg) {
    const int xcd = blockIdx.x & 7;
    const int j = blockIdx.x >> 3;
    const int bpg = npg >> 2;
    const int graph = xcd * (BATCH / 8) + j / bpg;
    const int nblk = j - (j / bpg) * bpg;
    const int wid = graph * npg + nblk * 4 + (threadIdx.x >> 6);
    const int lane = threadIdx.x & 63;

    const int start = csr_off[wid];
    const int deg = csr_deg[wid];
    const size_t fo = (size_t)lane * 2;
    float a0 = 0.f, a1 = 0.f, b0 = 0.f, b1 = 0.f;
    float c0 = 0.f, c1 = 0.f, d0 = 0.f, d1 = 0.f;
    int e = 0;
    for (; e + 4 <= deg; e += 4) {
        int s0 = csr_src[start + e];
        int s1 = csr_src[start + e + 1];
        int s2 = csr_src[start + e + 2];
        int s3 = csr_src[start + e + 3];
        float2 v0 = *(const float2*)&t_rel[(size_t)s0 * 128 + fo];
        float2 v1 = *(const float2*)&t_rel[(size_t)s1 * 128 + fo];
        float2 v2 = *(const float2*)&t_rel[(size_t)s2 * 128 + fo];
        float2 v3 = *(const float2*)&t_rel[(size_t)s3 * 128 + fo];
        a0 += v0.x; a1 += v0.y;
        b0 += v1.x; b1 += v1.y;
        c0 += v2.x; c1 += v2.y;
        d0 += v3.x; d1 += v3.y;
    }
    for (; e < deg; e++) {
        int s0 = csr_src[start + e];
        float2 v0 = *(const float2*)&t_rel[(size_t)s0 * 128 + fo];
        a0 += v0.x; a1 += v0.y;
    }
    a0 += b0 + c0 + d0;
    a1 += b1 + c1 + d1;

    float2 bb = *(const float2*)&bias[fo];
    size_t o = (size_t)wid * 128 + fo;
    float2 hv = *(const float2*)&h[o];
    hv.x = fmaxf(hv.x + a0 + bb.x, 0.f);
    hv.y = fmaxf(hv.y + a1 + bb.y, 0.f);
    *(float2*)&h[o] = hv;
    float2 pp = *(const float2*)&pw[fo];
    float d = hv.x * pp.x + hv.y * pp.y;
    float nr = pp.x * pp.x + pp.y * pp.y;
#pragma unroll
    for (int off = 32; off; off >>= 1) {
        d += __shfl_down(d, off, 64);
        nr += __shfl_down(nr, off, 64);
    }
    if (lane == 0) sc[wid] = d / (sqrtf(nr) + 1e-16f);
}

// ---------------- fused topk + pool/readout + edge-remap/CSR ---------------
// One block per graph, 1024 threads. mode: 0=L1 (edges from gsrc/gdst),
// 1=L2 (edges from es/ed/em in-place), 2=L3 (no remap, no hp write).
__device__ __forceinline__ bool rank_before(float as, int ai, float bs, int bi) {
    return (as > bs) || (as == bs && ai < bi);
}
__global__ __launch_bounds__(1024) void topk_pool(
    const float* __restrict__ sc, const float* __restrict__ h,
    float* __restrict__ hp, float* __restrict__ z,
    const int* __restrict__ gsrc, const int* __restrict__ gdst,
    int* __restrict__ es, int* __restrict__ ed, int* __restrict__ em,
    int* __restrict__ csr_off, int* __restrict__ csr_deg, int* __restrict__ csr_src,
    int npg, int k, int mode) {
    __shared__ float sk[512];
    __shared__ int si[512];
    __shared__ int nid[NPER];
    __shared__ float tgs[K1];
    __shared__ int packed[EPG];
    __shared__ int cnt[K1];
    __shared__ int cur[K1];
    __shared__ int sscan[512];
    __shared__ float pmx[8][128], psm[8][128];
    const int g = blockIdx.x;
    const int t = threadIdx.x;

    // ---- phase 1: sort scores (desc, index tiebreak) ----
    if (t < 512) {
        sk[t] = (t < npg) ? sc[g * npg + t] : -INFINITY;
        si[t] = t;
    }
    __syncthreads();
    for (int size = 2; size <= 512; size <<= 1) {
        for (int stride = size >> 1; stride; stride >>= 1) {
            if (t < 512) {
                int i = t, j = i ^ stride;
                if (j > i) {
                    bool up = ((i & size) == 0);
                    float a = sk[i], b = sk[j];
                    int ai = si[i], bi = si[j];
                    bool doswap = up ? rank_before(b, bi, a, ai)
                                     : rank_before(a, ai, b, bi);
                    if (doswap) { sk[i] = b; sk[j] = a; si[i] = bi; si[j] = ai; }
                }
            }
            __syncthreads();
        }
    }
    // ---- phase 2: newid + tanh gates ----
    if (t < 512) {
        int orig = si[t];
        if (orig < npg) nid[orig] = (t < k) ? t : -1;
        if (t < k) tgs[t] = tanhf(sk[t]);
    }
    if (t < K1) cnt[t] = 0;
    __syncthreads();

    // ---- phase 3: pool + readout (+hp for next layer) ----
    {
        const int f = t & 127;
        const int jq = t >> 7;     // 0..7
        float mx = -INFINITY, sm = 0.f;
        for (int j = jq; j < k; j += 8) {
            float v = h[(size_t)(g * npg + si[j]) * 128 + f] * tgs[j];
            if (mode != 2) hp[(size_t)(g * k + j) * 128 + f] = v;
            mx = fmaxf(mx, v);
            sm += v;
        }
        pmx[jq][f] = mx; psm[jq][f] = sm;
        __syncthreads();
        if (t < 128) {
            mx = pmx[0][t]; sm = psm[0][t];
#pragma unroll
            for (int q = 1; q < 8; q++) {
                mx = fmaxf(mx, pmx[q][t]);
                sm += psm[q][t];
            }
            z[g * 256 + t] += mx;
            z[g * 256 + 128 + t] += sm / (float)k;
        }
    }
    if (mode == 2) return;

    // ---- phase 4: edge remap + CSR build over pooled node space ----
    for (int e = t; e < EPG; e += 1024) {
        int eg = g * EPG + e;
        int sl, dl, m;
        if (mode == 0) { sl = gsrc[eg] - g * NPER; dl = gdst[eg] - g * NPER; m = 1; }
        else           { sl = es[eg]; dl = ed[eg]; m = em[eg]; }
        int ns = nid[sl], nd = nid[dl];
        int keep = (m && ns >= 0 && nd >= 0) ? 1 : 0;
        es[eg] = keep ? ns : 0;
        ed[eg] = keep ? nd : 0;
        em[eg] = keep;
        packed[e] = keep ? (ns | (nd << 16)) : -1;
        if (keep) atomicAdd(&cnt[nd], 1);
    }
    __syncthreads();
    if (t < 512) sscan[t] = (t < k) ? cnt[t] : 0;
    __syncthreads();
    for (int d = 1; d < 512; d <<= 1) {
        int v = 0;
        if (t < 512 && t >= d) v = sscan[t - d];
        __syncthreads();
        if (t < 512 && t >= d) sscan[t] += v;
        __syncthreads();
    }
    if (t < k) {
        int excl = (t == 0) ? 0 : sscan[t - 1];
        int st = g * EPG + excl;
        csr_off[g * k + t] = st;
        csr_deg[g * k + t] = cnt[t];
        cur[t] = st;
    }
    __syncthreads();
    for (int e = t; e < EPG; e += 1024) {
        int p = packed[e];
        if (p >= 0) {
            int ns = p & 0xffff, nd = p >> 16;
            int slot = atomicAdd(&cur[nd], 1);
            csr_src[slot] = g * k + ns;
        }
    }
}

// ---------------- MLP head + log_softmax ----------------
__global__ __launch_bounds__(256) void mlp_head(const float* __restrict__ z,
                                                const float* __restrict__ W1,
                                                const float* __restrict__ bl1,
                                                const float* __restrict__ W2,
                                                const float* __restrict__ bl2,
                                                const float* __restrict__ W3,
                                                const float* __restrict__ bl3,
                                                float* __restrict__ out) {
    __shared__ float zs[256], l1[128], l2[64];
    const int g = blockIdx.x, t = threadIdx.x;
    zs[t] = z[g * 256 + t];
    __syncthreads();
    if (t < 128) {
        float s = bl1[t];
        const float* w = &W1[t * 256];
        for (int i = 0; i < 256; i++) s += w[i] * zs[i];
        l1[t] = fmaxf(s, 0.f);
    }
    __syncthreads();
    if (t < 64) {
        float s = bl2[t];
        const float* w = &W2[t * 128];
        for (int i = 0; i < 128; i++) s += w[i] * l1[i];
        l2[t] = fmaxf(s, 0.f);
    }
    __syncthreads();
    if (t == 0) {
        float a = bl3[0], b = bl3[1];
        for (int i = 0; i < 64; i++) { a += W3[i] * l2[i]; b += W3[64 + i] * l2[i]; }
        float m = fmaxf(a, b);
        float lse = m + logf(expf(a - m) + expf(b - m));
        out[g * 2 + 0] = a - lse;
        out[g * 2 + 1] = b - lse;
    }
}

// ---------------- launch ----------------
extern "C" void kernel_launch(void* const* d_in, const int* in_sizes, int n_in,
                              void* d_out, int out_size, void* d_ws, size_t ws_size,
                              hipStream_t stream) {
    const float* x        = (const float*)d_in[0];
    const int*   edge_src = (const int*)d_in[1];
    const int*   edge_dst = (const int*)d_in[2];
    const float* Wrel1 = (const float*)d_in[4];
    const float* Wroot1= (const float*)d_in[5];
    const float* b1    = (const float*)d_in[6];
    const float* pw1   = (const float*)d_in[7];
    const float* Wrel2 = (const float*)d_in[8];
    const float* Wroot2= (const float*)d_in[9];
    const float* b2    = (const float*)d_in[10];
    const float* pw2   = (const float*)d_in[11];
    const float* Wrel3 = (const float*)d_in[12];
    const float* Wroot3= (const float*)d_in[13];
    const float* b3    = (const float*)d_in[14];
    const float* pw3   = (const float*)d_in[15];
    const float* W1    = (const float*)d_in[16];
    const float* bl1   = (const float*)d_in[17];
    const float* W2    = (const float*)d_in[18];
    const float* bl2   = (const float*)d_in[19];
    const float* W3    = (const float*)d_in[20];
    const float* bl3   = (const float*)d_in[21];

    char* ws = (char*)d_ws;
    float* t_rel = (float*)(ws + OFF_TREL);
    float* h     = (float*)(ws + OFF_H);
    float* hp    = (float*)(ws + OFF_HP);
    float* sc    = (float*)(ws + OFF_SC);
    int*   es    = (int*)(ws + OFF_ES);
    int*   ed    = (int*)(ws + OFF_ED);
    int*   em    = (int*)(ws + OFF_EM);
    float* z     = (float*)(ws + OFF_Z);
    int*   coff  = (int*)(ws + OFF_COFF);
    int*   cdeg  = (int*)(ws + OFF_CDEG);
    int*   csrc  = (int*)(ws + OFF_CSRC);
    unsigned short* w1h = (unsigned short*)(ws + OFF_W1H);
    unsigned short* w1l = (unsigned short*)(ws + OFF_W1L);
    unsigned short* w2h = (unsigned short*)(ws + OFF_W2H);
    unsigned short* w2l = (unsigned short*)(ws + OFF_W2L);
    unsigned short* w3h = (unsigned short*)(ws + OFF_W3H);
    unsigned short* w3l = (unsigned short*)(ws + OFF_W3L);

    hipMemsetAsync(z, 0, 128ull * 256 * 4, stream);
    prep_w_all<<<dim3(13, 16, 3), 64, 0, stream>>>(
        Wrel1, Wroot1, Wrel2, Wroot2, Wrel3, Wroot3,
        w1h, w1l, w2h, w2l, w3h, w3l);
    csr_build0<<<BATCH, 1024, 0, stream>>>(edge_src, edge_dst, coff, cdeg, csrc);

    // ---------- layer 1 ----------
    gemm_mfma<13, F_IN><<<800, 256, 0, stream>>>(x, w1h, w1l, t_rel, h);
    agg_score<<<51200 / 4, 256, 0, stream>>>(t_rel, coff, cdeg, csrc, b1, pw1,
                                             h, sc, NPER);
    topk_pool<<<BATCH, 1024, 0, stream>>>(sc, h, hp, z, edge_src, edge_dst,
                                          es, ed, em, coff, cdeg, csrc,
                                          NPER, K1, 0);

    // ---------- layer 2 ----------
    gemm_mfma<4, HD><<<640, 256, 0, stream>>>(hp, w2h, w2l, t_rel, h);
    agg_score<<<40960 / 4, 256, 0, stream>>>(t_rel, coff, cdeg, csrc, b2, pw2,
                                             h, sc, K1);
    topk_pool<<<BATCH, 1024, 0, stream>>>(sc, h, hp, z, nullptr, nullptr,
                                          es, ed, em, coff, cdeg, csrc,
                                          K1, K2, 1);

    // ---------- layer 3 ----------
    gemm_mfma<4, HD><<<512, 256, 0, stream>>>(hp, w3h, w3l, t_rel, h);
    agg_score<<<32768 / 4, 256, 0, stream>>>(t_rel, coff, cdeg, csrc, b3, pw3,
                                             h, sc, K2);
    topk_pool<<<BATCH, 1024, 0, stream>>>(sc, h, nullptr, z, nullptr, nullptr,
                                          es, ed, em, coff, cdeg, csrc,
                                          K2, K3, 2);

    // ---------- MLP head ----------
    mlp_head<<<BATCH, 256, 0, stream>>>(z, W1, bl1, W2, bl2, W3, bl3, (float*)d_out);
}

// Round 4
// 444.236 us; speedup vs baseline: 1.0623x; 1.0623x over previous
//
#include <hip/hip_runtime.h>
#include <math.h>

// Problem constants
#define BATCH 128
#define NPER 400
#define EPG 6400
#define NEDGE 819200
#define F_IN 400
#define HD 128
#define K1 320
#define K2 256
#define K3 205

typedef __bf16 bf16x8 __attribute__((ext_vector_type(8)));
typedef float f32x4 __attribute__((ext_vector_type(4)));

__device__ __forceinline__ unsigned short f2bf(float f) {
    unsigned u = __builtin_bit_cast(unsigned, f);
    unsigned r = u + 0x7fffu + ((u >> 16) & 1u);
    return (unsigned short)(r >> 16);
}
__device__ __forceinline__ float bf2f(unsigned short s) {
    unsigned u = ((unsigned)s) << 16;
    return __builtin_bit_cast(float, u);
}

// ---------------- workspace layout ----------------
static constexpr size_t SZ_TREL = 51200ull * 128 * 4;
static constexpr size_t OFF_TREL = 0;
static constexpr size_t OFF_H    = OFF_TREL + SZ_TREL;
static constexpr size_t OFF_HP   = OFF_H + SZ_TREL;
static constexpr size_t OFF_SC   = OFF_HP + 40960ull * 128 * 4;
static constexpr size_t OFF_ES   = OFF_SC + 51200ull * 4;
static constexpr size_t OFF_ED   = OFF_ES + (size_t)NEDGE * 4;
static constexpr size_t OFF_EM   = OFF_ED + (size_t)NEDGE * 4;
static constexpr size_t OFF_Z    = OFF_EM + (size_t)NEDGE * 4;
static constexpr size_t OFF_COFF = OFF_Z + 128ull * 256 * 4;
static constexpr size_t OFF_CDEG = OFF_COFF + 51200ull * 4;
static constexpr size_t OFF_CSRC = OFF_CDEG + 51200ull * 4;
static constexpr size_t OFF_W1H  = OFF_CSRC + (size_t)NEDGE * 4;   // 16*13*512 shorts
static constexpr size_t OFF_W1L  = OFF_W1H + 16ull * 13 * 512 * 2;
static constexpr size_t OFF_W2H  = OFF_W1L + 16ull * 13 * 512 * 2;
static constexpr size_t OFF_W2L  = OFF_W2H + 16ull * 4 * 512 * 2;
static constexpr size_t OFF_W3H  = OFF_W2L + 16ull * 4 * 512 * 2;
static constexpr size_t OFF_W3L  = OFF_W3H + 16ull * 4 * 512 * 2;

// ---------------- weight split + fragment-tile prep (all 3 layers) ---------
// chunk[(n_tile*Ks + s)*512 + lane*8 + e] = B[n_tile*16 + (lane&15)][s*32 + (lane>>4)*8 + e]
__global__ __launch_bounds__(64) void prep_w_all(
    const float* __restrict__ Wrel1, const float* __restrict__ Wroot1,
    const float* __restrict__ Wrel2, const float* __restrict__ Wroot2,
    const float* __restrict__ Wrel3, const float* __restrict__ Wroot3,
    unsigned short* __restrict__ b1h, unsigned short* __restrict__ b1l,
    unsigned short* __restrict__ b2h, unsigned short* __restrict__ b2l,
    unsigned short* __restrict__ b3h, unsigned short* __restrict__ b3l) {
    const int layer = blockIdx.z;
    const int s = blockIdx.x;
    const int ntile = blockIdx.y;
    const int Ks = (layer == 0) ? 13 : 4;
    const int Kd = (layer == 0) ? F_IN : HD;
    if (s >= Ks) return;
    const float* Wrel  = (layer == 0) ? Wrel1  : (layer == 1) ? Wrel2  : Wrel3;
    const float* Wroot = (layer == 0) ? Wroot1 : (layer == 1) ? Wroot2 : Wroot3;
    unsigned short* bh = (layer == 0) ? b1h : (layer == 1) ? b2h : b3h;
    unsigned short* bl = (layer == 0) ? b1l : (layer == 1) ? b2l : b3l;
    const int t = threadIdx.x;
    const int rowin = t & 15, qd = t >> 4;
    const int n = ntile * 16 + rowin;
    const int k = s * 32 + qd * 8;
    const float* src = (n < 128) ? &Wrel[(n & 127) * Kd] : &Wroot[(n & 127) * Kd];
    unsigned short hv[8], lv[8];
#pragma unroll
    for (int e = 0; e < 8; e++) {
        float f = (k + e < Kd) ? src[k + e] : 0.f;
        unsigned short hi = f2bf(f);
        hv[e] = hi;
        lv[e] = f2bf(f - bf2f(hi));
    }
    size_t o = ((size_t)ntile * Ks + s) * 512 + (size_t)t * 8;
#pragma unroll
    for (int e = 0; e < 8; e++) { bh[o + e] = hv[e]; bl[o + e] = lv[e]; }
}

// ---------------- MFMA GEMM (split-once-in-LDS bf16 fragment buffer) -------
// 1-D grid M/64. Block 256 thr = 4 waves sharing the same 64 A-rows.
// Per K-step the 64x32 f32 A-tile is reg-staged (issued 2 steps ahead),
// converted ONCE to bf16 hi/lo by the whole block (8 elems/thread), and
// ds_written into a fragment-linear LDS layout:
//   slot(i,qd,lm) at byte i*1024 + qd*256 + lm*16  (hi at +0, lo at +4096)
// Wave frag read addr = buf + i*1024 + lane*16 -> lane-linear, conflict-free.
// This removes the 4x-redundant per-wave split VALU (was ~100 ops/lane/step,
// now 24) and shrinks live registers so 3 blocks/CU fit WITHOUT spills.
// Raw s_barrier with lgkmcnt(0)-only drain: A-prefetch (2 ahead) and B loads
// stay in flight across barriers; vmcnt never drains to 0 in the loop.
template <int Ks, int Kd>
__global__ __launch_bounds__(256, 3) void gemm_mfma(
    const float* __restrict__ A,
    const unsigned short* __restrict__ bh_p, const unsigned short* __restrict__ bl_p,
    float* __restrict__ t_rel, float* __restrict__ h) {
    __shared__ char Alds[2][8192];   // [buf][hi 4KB | lo 4KB]
    const int tid = threadIdx.x;
    const int lane = tid & 63;
    const int wv = tid >> 6;
    const int lm = lane & 15;
    const int qd = (lane >> 4) & 3;
    const int m0 = blockIdx.x * 64;
    const int nt0 = wv * 4;

    // staging: thread owns row srow = tid>>2 (0..63), k-quarter sqd = tid&3
    const int srow = tid >> 2;
    const int sqd = tid & 3;
    const int woff = ((srow >> 4) << 10) + (sqd << 8) + ((srow & 15) << 4);
    const float* Arow = A + (size_t)(m0 + srow) * Kd + sqd * 8;

    f32x4 acc[4][4];
#pragma unroll
    for (int i = 0; i < 4; i++)
#pragma unroll
        for (int j = 0; j < 4; j++) acc[i][j] = (f32x4){0.f, 0.f, 0.f, 0.f};

    auto gload = [&](int s, float4& x0, float4& x1) {
        if (s * 32 + sqd * 8 < Kd) {   // Kd % 8 == 0: per-thread all-or-nothing
            const float* p = Arow + s * 32;
            x0 = *(const float4*)p;
            x1 = *(const float4*)(p + 4);
        } else {
            x0 = make_float4(0.f, 0.f, 0.f, 0.f);
            x1 = x0;
        }
    };
    auto cvwrite = [&](int buf, const float4& x0, const float4& x1) {
        float fe[8] = {x0.x, x0.y, x0.z, x0.w, x1.x, x1.y, x1.z, x1.w};
        bf16x8 hv, lv;
#pragma unroll
        for (int e = 0; e < 8; e++) {
            __bf16 hb = (__bf16)fe[e];
            hv[e] = hb;
            lv[e] = (__bf16)(fe[e] - (float)hb);
        }
        *(bf16x8*)(&Alds[buf][woff]) = hv;
        *(bf16x8*)(&Alds[buf][4096 + woff]) = lv;
    };

    // prologue: tiles 0 and 1 into regs, convert tile 0 into buf0
    float4 r0a, r0b, r1a, r1b;   // reg buffer parity: tile s -> (s&1)
    gload(0, r0a, r0b);
    if (Ks > 1) gload(1, r1a, r1b);
    cvwrite(0, r0a, r0b);
    asm volatile("s_waitcnt lgkmcnt(0)" ::: "memory");
    __builtin_amdgcn_s_barrier();
    asm volatile("" ::: "memory");

#pragma unroll
    for (int s = 0; s < Ks; ++s) {
        // ---- B fragment loads for THIS step (issued first: latency budget) --
        bf16x8 bhc[4], blc[4];
#pragma unroll
        for (int j = 0; j < 4; j++)
            bhc[j] = *(const bf16x8*)&bh_p[((size_t)(nt0 + j) * Ks + s) * 512 + lane * 8];
#pragma unroll
        for (int j = 0; j < 4; j++)
            blc[j] = *(const bf16x8*)&bl_p[((size_t)(nt0 + j) * Ks + s) * 512 + lane * 8];

        // ---- A fragment ds_reads (lane-linear, conflict-free) ----
        const char* Ab = &Alds[s & 1][0];
        bf16x8 ah[4], al[4];
#pragma unroll
        for (int i = 0; i < 4; i++) {
            ah[i] = *(const bf16x8*)(Ab + i * 1024 + lane * 16);
            al[i] = *(const bf16x8*)(Ab + 4096 + i * 1024 + lane * 16);
        }

        // ---- convert tile s+1 into the other buffer; prefetch tile s+2 ----
        if (s + 1 < Ks) {
            if ((s + 1) & 1) cvwrite((s + 1) & 1, r1a, r1b);
            else             cvwrite((s + 1) & 1, r0a, r0b);
        }
        if (s + 2 < Ks) {
            if ((s + 2) & 1) gload(s + 2, r1a, r1b);
            else             gload(s + 2, r0a, r0b);
        }

        // ---- MFMA: hi*hi + lo*hi + hi*lo (order preserved for numerics) ----
        __builtin_amdgcn_s_setprio(1);
#pragma unroll
        for (int j = 0; j < 4; j++)
#pragma unroll
            for (int i = 0; i < 4; i++)
                acc[i][j] = __builtin_amdgcn_mfma_f32_16x16x32_bf16(
                    ah[i], bhc[j], acc[i][j], 0, 0, 0);
#pragma unroll
        for (int j = 0; j < 4; j++)
#pragma unroll
            for (int i = 0; i < 4; i++)
                acc[i][j] = __builtin_amdgcn_mfma_f32_16x16x32_bf16(
                    al[i], bhc[j], acc[i][j], 0, 0, 0);
#pragma unroll
        for (int j = 0; j < 4; j++)
#pragma unroll
            for (int i = 0; i < 4; i++)
                acc[i][j] = __builtin_amdgcn_mfma_f32_16x16x32_bf16(
                    ah[i], blc[j], acc[i][j], 0, 0, 0);
        __builtin_amdgcn_s_setprio(0);

        // ---- drain LDS ops (writes visible), barrier; vmcnt stays in flight
        asm volatile("s_waitcnt lgkmcnt(0)" ::: "memory");
        __builtin_amdgcn_s_barrier();
        asm volatile("" ::: "memory");
    }
    // ---- epilogue: C/D layout col=lane&15, row=qd*4+reg ----
    float* out = (wv < 2) ? t_rel : h;
    const int colbase = (wv & 1) * 64;
#pragma unroll
    for (int i = 0; i < 4; i++)
#pragma unroll
        for (int j = 0; j < 4; j++) {
            int row = m0 + i * 16 + qd * 4;
            int col = colbase + j * 16 + lm;
#pragma unroll
            for (int r = 0; r < 4; r++)
                out[(size_t)(row + r) * 128 + col] = acc[i][j][r];
        }
}

// ---------------- CSR build for layer 1 (original edges, no mask) ----------
__global__ __launch_bounds__(1024) void csr_build0(
    const int* __restrict__ gsrc, const int* __restrict__ gdst,
    int* __restrict__ csr_off, int* __restrict__ csr_deg, int* __restrict__ csr_src) {
    __shared__ int cnt[NPER];
    __shared__ int cur[NPER];
    __shared__ int sscan[512];
    const int g = blockIdx.x;
    const int t = threadIdx.x;
    for (int i = t; i < NPER; i += 1024) cnt[i] = 0;
    __syncthreads();
    for (int e = t; e < EPG; e += 1024) {
        int dl = gdst[g * EPG + e] - g * NPER;
        atomicAdd(&cnt[dl], 1);
    }
    __syncthreads();
    if (t < 512) sscan[t] = (t < NPER) ? cnt[t] : 0;
    __syncthreads();
    for (int d = 1; d < 512; d <<= 1) {
        int v = 0;
        if (t < 512 && t >= d) v = sscan[t - d];
        __syncthreads();
        if (t < 512 && t >= d) sscan[t] += v;
        __syncthreads();
    }
    if (t < NPER) {
        int excl = (t == 0) ? 0 : sscan[t - 1];
        int st = g * EPG + excl;
        csr_off[g * NPER + t] = st;
        csr_deg[g * NPER + t] = cnt[t];
        cur[t] = st;
    }
    __syncthreads();
    for (int e = t; e < EPG; e += 1024) {
        int eg = g * EPG + e;
        int dl = gdst[eg] - g * NPER;
        int slot = atomicAdd(&cur[dl], 1);
        csr_src[slot] = gsrc[eg];
    }
}

// ---------------- Aggregation (gather) + combine + relu + score ------------
__global__ __launch_bounds__(256) void agg_score(
    const float* __restrict__ t_rel,
    const int* __restrict__ csr_off, const int* __restrict__ csr_deg,
    const int* __restrict__ csr_src,
    const float* __restrict__ bias, const float* __restrict__ pw,
    float* __restrict__ h, float* __restrict__ sc, int npg) {
    const int xcd = blockIdx.x & 7;
    const int j = blockIdx.x >> 3;
    const int bpg = npg >> 2;
    const int graph = xcd * (BATCH / 8) + j / bpg;
    const int nblk = j - (j / bpg) * bpg;
    const int wid = graph * npg + nblk * 4 + (threadIdx.x >> 6);
    const int lane = threadIdx.x & 63;

    const int start = csr_off[wid];
    const int deg = csr_deg[wid];
    const size_t fo = (size_t)lane * 2;
    float a0 = 0.f, a1 = 0.f, b0 = 0.f, b1 = 0.f;
    float c0 = 0.f, c1 = 0.f, d0 = 0.f, d1 = 0.f;
    int e = 0;
    for (; e + 4 <= deg; e += 4) {
        int s0 = csr_src[start + e];
        int s1 = csr_src[start + e + 1];
        int s2 = csr_src[start + e + 2];
        int s3 = csr_src[start + e + 3];
        float2 v0 = *(const float2*)&t_rel[(size_t)s0 * 128 + fo];
        float2 v1 = *(const float2*)&t_rel[(size_t)s1 * 128 + fo];
        float2 v2 = *(const float2*)&t_rel[(size_t)s2 * 128 + fo];
        float2 v3 = *(const float2*)&t_rel[(size_t)s3 * 128 + fo];
        a0 += v0.x; a1 += v0.y;
        b0 += v1.x; b1 += v1.y;
        c0 += v2.x; c1 += v2.y;
        d0 += v3.x; d1 += v3.y;
    }
    for (; e < deg; e++) {
        int s0 = csr_src[start + e];
        float2 v0 = *(const float2*)&t_rel[(size_t)s0 * 128 + fo];
        a0 += v0.x; a1 += v0.y;
    }
    a0 += b0 + c0 + d0;
    a1 += b1 + c1 + d1;

    float2 bb = *(const float2*)&bias[fo];
    size_t o = (size_t)wid * 128 + fo;
    float2 hv = *(const float2*)&h[o];
    hv.x = fmaxf(hv.x + a0 + bb.x, 0.f);
    hv.y = fmaxf(hv.y + a1 + bb.y, 0.f);
    *(float2*)&h[o] = hv;
    float2 pp = *(const float2*)&pw[fo];
    float d = hv.x * pp.x + hv.y * pp.y;
    float nr = pp.x * pp.x + pp.y * pp.y;
#pragma unroll
    for (int off = 32; off; off >>= 1) {
        d += __shfl_down(d, off, 64);
        nr += __shfl_down(nr, off, 64);
    }
    if (lane == 0) sc[wid] = d / (sqrtf(nr) + 1e-16f);
}

// ---------------- fused topk + pool/readout + edge-remap/CSR ---------------
// One block per graph, 1024 threads. mode: 0=L1 (edges from gsrc/gdst),
// 1=L2 (edges from es/ed/em in-place), 2=L3 (no remap, no hp write).
__device__ __forceinline__ bool rank_before(float as, int ai, float bs, int bi) {
    return (as > bs) || (as == bs && ai < bi);
}
__global__ __launch_bounds__(1024) void topk_pool(
    const float* __restrict__ sc, const float* __restrict__ h,
    float* __restrict__ hp, float* __restrict__ z,
    const int* __restrict__ gsrc, const int* __restrict__ gdst,
    int* __restrict__ es, int* __restrict__ ed, int* __restrict__ em,
    int* __restrict__ csr_off, int* __restrict__ csr_deg, int* __restrict__ csr_src,
    int npg, int k, int mode) {
    __shared__ float sk[512];
    __shared__ int si[512];
    __shared__ int nid[NPER];
    __shared__ float tgs[K1];
    __shared__ int packed[EPG];
    __shared__ int cnt[K1];
    __shared__ int cur[K1];
    __shared__ int sscan[512];
    __shared__ float pmx[8][128], psm[8][128];
    const int g = blockIdx.x;
    const int t = threadIdx.x;

    // ---- phase 1: sort scores (desc, index tiebreak) ----
    if (t < 512) {
        sk[t] = (t < npg) ? sc[g * npg + t] : -INFINITY;
        si[t] = t;
    }
    __syncthreads();
    for (int size = 2; size <= 512; size <<= 1) {
        for (int stride = size >> 1; stride; stride >>= 1) {
            if (t < 512) {
                int i = t, j = i ^ stride;
                if (j > i) {
                    bool up = ((i & size) == 0);
                    float a = sk[i], b = sk[j];
                    int ai = si[i], bi = si[j];
                    bool doswap = up ? rank_before(b, bi, a, ai)
                                     : rank_before(a, ai, b, bi);
                    if (doswap) { sk[i] = b; sk[j] = a; si[i] = bi; si[j] = ai; }
                }
            }
            __syncthreads();
        }
    }
    // ---- phase 2: newid + tanh gates ----
    if (t < 512) {
        int orig = si[t];
        if (orig < npg) nid[orig] = (t < k) ? t : -1;
        if (t < k) tgs[t] = tanhf(sk[t]);
    }
    if (t < K1) cnt[t] = 0;
    __syncthreads();

    // ---- phase 3: pool + readout (+hp for next layer) ----
    {
        const int f = t & 127;
        const int jq = t >> 7;     // 0..7
        float mx = -INFINITY, sm = 0.f;
        for (int j = jq; j < k; j += 8) {
            float v = h[(size_t)(g * npg + si[j]) * 128 + f] * tgs[j];
            if (mode != 2) hp[(size_t)(g * k + j) * 128 + f] = v;
            mx = fmaxf(mx, v);
            sm += v;
        }
        pmx[jq][f] = mx; psm[jq][f] = sm;
        __syncthreads();
        if (t < 128) {
            mx = pmx[0][t]; sm = psm[0][t];
#pragma unroll
            for (int q = 1; q < 8; q++) {
                mx = fmaxf(mx, pmx[q][t]);
                sm += psm[q][t];
            }
            z[g * 256 + t] += mx;
            z[g * 256 + 128 + t] += sm / (float)k;
        }
    }
    if (mode == 2) return;

    // ---- phase 4: edge remap + CSR build over pooled node space ----
    for (int e = t; e < EPG; e += 1024) {
        int eg = g * EPG + e;
        int sl, dl, m;
        if (mode == 0) { sl = gsrc[eg] - g * NPER; dl = gdst[eg] - g * NPER; m = 1; }
        else           { sl = es[eg]; dl = ed[eg]; m = em[eg]; }
        int ns = nid[sl], nd = nid[dl];
        int keep = (m && ns >= 0 && nd >= 0) ? 1 : 0;
        es[eg] = keep ? ns : 0;
        ed[eg] = keep ? nd : 0;
        em[eg] = keep;
        packed[e] = keep ? (ns | (nd << 16)) : -1;
        if (keep) atomicAdd(&cnt[nd], 1);
    }
    __syncthreads();
    if (t < 512) sscan[t] = (t < k) ? cnt[t] : 0;
    __syncthreads();
    for (int d = 1; d < 512; d <<= 1) {
        int v = 0;
        if (t < 512 && t >= d) v = sscan[t - d];
        __syncthreads();
        if (t < 512 && t >= d) sscan[t] += v;
        __syncthreads();
    }
    if (t < k) {
        int excl = (t == 0) ? 0 : sscan[t - 1];
        int st = g * EPG + excl;
        csr_off[g * k + t] = st;
        csr_deg[g * k + t] = cnt[t];
        cur[t] = st;
    }
    __syncthreads();
    for (int e = t; e < EPG; e += 1024) {
        int p = packed[e];
        if (p >= 0) {
            int ns = p & 0xffff, nd = p >> 16;
            int slot = atomicAdd(&cur[nd], 1);
            csr_src[slot] = g * k + ns;
        }
    }
}

// ---------------- MLP head + log_softmax ----------------
__global__ __launch_bounds__(256) void mlp_head(const float* __restrict__ z,
                                                const float* __restrict__ W1,
                                                const float* __restrict__ bl1,
                                                const float* __restrict__ W2,
                                                const float* __restrict__ bl2,
                                                const float* __restrict__ W3,
                                                const float* __restrict__ bl3,
                                                float* __restrict__ out) {
    __shared__ float zs[256], l1[128], l2[64];
    const int g = blockIdx.x, t = threadIdx.x;
    zs[t] = z[g * 256 + t];
    __syncthreads();
    if (t < 128) {
        float s = bl1[t];
        const float* w = &W1[t * 256];
        for (int i = 0; i < 256; i++) s += w[i] * zs[i];
        l1[t] = fmaxf(s, 0.f);
    }
    __syncthreads();
    if (t < 64) {
        float s = bl2[t];
        const float* w = &W2[t * 128];
        for (int i = 0; i < 128; i++) s += w[i] * l1[i];
        l2[t] = fmaxf(s, 0.f);
    }
    __syncthreads();
    if (t == 0) {
        float a = bl3[0], b = bl3[1];
        for (int i = 0; i < 64; i++) { a += W3[i] * l2[i]; b += W3[64 + i] * l2[i]; }
        float m = fmaxf(a, b);
        float lse = m + logf(expf(a - m) + expf(b - m));
        out[g * 2 + 0] = a - lse;
        out[g * 2 + 1] = b - lse;
    }
}

// ---------------- launch ----------------
extern "C" void kernel_launch(void* const* d_in, const int* in_sizes, int n_in,
                              void* d_out, int out_size, void* d_ws, size_t ws_size,
                              hipStream_t stream) {
    const float* x        = (const float*)d_in[0];
    const int*   edge_src = (const int*)d_in[1];
    const int*   edge_dst = (const int*)d_in[2];
    const float* Wrel1 = (const float*)d_in[4];
    const float* Wroot1= (const float*)d_in[5];
    const float* b1    = (const float*)d_in[6];
    const float* pw1   = (const float*)d_in[7];
    const float* Wrel2 = (const float*)d_in[8];
    const float* Wroot2= (const float*)d_in[9];
    const float* b2    = (const float*)d_in[10];
    const float* pw2   = (const float*)d_in[11];
    const float* Wrel3 = (const float*)d_in[12];
    const float* Wroot3= (const float*)d_in[13];
    const float* b3    = (const float*)d_in[14];
    const float* pw3   = (const float*)d_in[15];
    const float* W1    = (const float*)d_in[16];
    const float* bl1   = (const float*)d_in[17];
    const float* W2    = (const float*)d_in[18];
    const float* bl2   = (const float*)d_in[19];
    const float* W3    = (const float*)d_in[20];
    const float* bl3   = (const float*)d_in[21];

    char* ws = (char*)d_ws;
    float* t_rel = (float*)(ws + OFF_TREL);
    float* h     = (float*)(ws + OFF_H);
    float* hp    = (float*)(ws + OFF_HP);
    float* sc    = (float*)(ws + OFF_SC);
    int*   es    = (int*)(ws + OFF_ES);
    int*   ed    = (int*)(ws + OFF_ED);
    int*   em    = (int*)(ws + OFF_EM);
    float* z     = (float*)(ws + OFF_Z);
    int*   coff  = (int*)(ws + OFF_COFF);
    int*   cdeg  = (int*)(ws + OFF_CDEG);
    int*   csrc  = (int*)(ws + OFF_CSRC);
    unsigned short* w1h = (unsigned short*)(ws + OFF_W1H);
    unsigned short* w1l = (unsigned short*)(ws + OFF_W1L);
    unsigned short* w2h = (unsigned short*)(ws + OFF_W2H);
    unsigned short* w2l = (unsigned short*)(ws + OFF_W2L);
    unsigned short* w3h = (unsigned short*)(ws + OFF_W3H);
    unsigned short* w3l = (unsigned short*)(ws + OFF_W3L);

    hipMemsetAsync(z, 0, 128ull * 256 * 4, stream);
    prep_w_all<<<dim3(13, 16, 3), 64, 0, stream>>>(
        Wrel1, Wroot1, Wrel2, Wroot2, Wrel3, Wroot3,
        w1h, w1l, w2h, w2l, w3h, w3l);
    csr_build0<<<BATCH, 1024, 0, stream>>>(edge_src, edge_dst, coff, cdeg, csrc);

    // ---------- layer 1 ----------
    gemm_mfma<13, F_IN><<<800, 256, 0, stream>>>(x, w1h, w1l, t_rel, h);
    agg_score<<<51200 / 4, 256, 0, stream>>>(t_rel, coff, cdeg, csrc, b1, pw1,
                                             h, sc, NPER);
    topk_pool<<<BATCH, 1024, 0, stream>>>(sc, h, hp, z, edge_src, edge_dst,
                                          es, ed, em, coff, cdeg, csrc,
                                          NPER, K1, 0);

    // ---------- layer 2 ----------
    gemm_mfma<4, HD><<<640, 256, 0, stream>>>(hp, w2h, w2l, t_rel, h);
    agg_score<<<40960 / 4, 256, 0, stream>>>(t_rel, coff, cdeg, csrc, b2, pw2,
                                             h, sc, K1);
    topk_pool<<<BATCH, 1024, 0, stream>>>(sc, h, hp, z, nullptr, nullptr,
                                          es, ed, em, coff, cdeg, csrc,
                                          K1, K2, 1);

    // ---------- layer 3 ----------
    gemm_mfma<4, HD><<<512, 256, 0, stream>>>(hp, w3h, w3l, t_rel, h);
    agg_score<<<32768 / 4, 256, 0, stream>>>(t_rel, coff, cdeg, csrc, b3, pw3,
                                             h, sc, K2);
    topk_pool<<<BATCH, 1024, 0, stream>>>(sc, h, nullptr, z, nullptr, nullptr,
                                          es, ed, em, coff, cdeg, csrc,
                                          K2, K3, 2);

    // ---------- MLP head ----------
    mlp_head<<<BATCH, 256, 0, stream>>>(z, W1, bl1, W2, bl2, W3, bl3, (float*)d_out);
}